// Round 11
// baseline (75.525 us; speedup 1.0000x reference)
//
#include <hip/hip_runtime.h>

// RNN-T (transducer) loss, B=8 T=256 U=96 H=512, f32.
// Linear-domain wavefront DP: A[t,u] = A[t-1,u]*Wb[t-1,u] + A[t,u-1]*We[t,u-1]
// Wb=exp(blank_lp), We=exp(emit_lp) precomputed by k_lse into diagonal layout:
// Wb(t,u) -> row t+u, col u, slot0;  We(t,u) -> row t+u, col u+1, slot1.
// Every cell k_alpha reads is zeroed or written each call (no stale/poison).
constexpr int B = 8, T = 256, U = 96, H = 512;
constexpr int RW = 96, ROWS = 368;   // float2 {wb,we} per cell

typedef float vf4 __attribute__((ext_vector_type(4)));

__device__ __forceinline__ float exp2i(int e) {      // e in [-126,127]
    return __uint_as_float((unsigned)(127 + e) << 23);
}

// Fetch row element i (wave-uniform-ish, per-half) from a half's registers.
__device__ __forceinline__ float half_get(vf4 a, vf4 b, vf4 c, vf4 d,
                                          int i, int h) {
    vf4 p = (i & 128) ? ((i & 256) ? d : b) : ((i & 256) ? c : a);
    int m = i & 3;
    float e = (m == 0) ? p.x : (m == 1) ? p.y : (m == 2) ? p.z : p.w;
    return __shfl(e, (h << 5) | ((i >> 2) & 31));
}

// Kernel 1: blocks <2048: one wave per 24-row chunk, 2 rows at a time via
// 32-lane halves (5-level reduce). Blocks >=2048: zero unowned cells
// (triangles, tail rows, and the col-0 We slots of rows 0..255).
__global__ __launch_bounds__(256) void k_lse(
    const float* __restrict__ x, const int* __restrict__ label,
    const int* __restrict__ f_len, const int* __restrict__ y_len,
    const int* __restrict__ blank_p, const float* __restrict__ lam_p,
    float* __restrict__ D)
{
    const int tid = threadIdx.x;
    if (blockIdx.x >= 2048) {            // zero-fill unowned cells, batch bb
        int bb = blockIdx.x - 2048;
        float2* D2 = (float2*)D + (size_t)bb * ROWS * RW;
        float2 z = {0.f, 0.f};
        for (int k = 0; k < 95; ++k)                 // cells (k,c), c>k
            if (tid < 95 - k) D2[k * RW + k + 1 + tid] = z;
        for (int k = 256; k < 351; ++k)              // cells (k,c), c<k-255
            if (tid < k - 255) D2[k * RW + tid] = z;
        for (int idx = tid; idx < 17 * RW; idx += 256)  // tail rows 351..367
            D2[351 * RW + idx] = z;
        if (tid < 256)                               // col-0 We(t,-1) slots
            ((float*)&D2[tid * RW])[1] = 0.f;
        return;
    }

    const int lane = tid & 63;
    const int l32  = lane & 31;
    const int h    = lane >> 5;
    const int chunk = (blockIdx.x << 2) | (tid >> 6);   // 0..8191
    const int b  = chunk & 7;                 // b fastest: balanced dead work
    const int t  = (chunk >> 3) & 255;
    const int u0 = (chunk >> 11) * 24;

    const int fb = f_len[b], yb = y_len[b];
    const bool live = (t < fb) && (u0 <= yb);
    const int nbl = live ? min(24, yb + 1 - u0) : 0;   // rows with Wb write
    const int nem = live ? min(24, yb - u0)     : 0;   // rows with We write

    size_t cc0 = ((size_t)b * ROWS + (t + u0)) * RW + u0;
    if (lane < 24) {                       // zero owned-but-unwritten slots
        size_t cz = cc0 + (size_t)lane * (RW + 1);
        if (lane >= nbl) D[cz * 2] = 0.f;
        if (lane >= nem) D[(cz + 1) * 2 + 1] = 0.f;
    }
    if (!live) return;

    const int ib   = blank_p[0];
    const float lam = lam_p[0];
    const float pen = lam * ((fb - 1.0f) * 0.5f) - lam * (float)t;

    int lbl_l = 0;                                     // labels u0..u0+23
    if (lane < 24 && (u0 + lane) < U - 1)
        lbl_l = label[b * (U - 1) + u0 + lane];

    const float* xrow = x + ((size_t)(b * T + t) * U + u0) * H;

    for (int i = 0; i < nbl; i += 2) {
        int row = i + h;                   // half h handles row i+h
        bool rv = row < nbl;
        const float* xr = xrow + (size_t)row * H;
        vf4 v0 = {0,0,0,0}, v1 = v0, v2 = v0, v3 = v0;
        if (rv) {
            v0 = __builtin_nontemporal_load((const vf4*)xr + l32);
            v1 = __builtin_nontemporal_load((const vf4*)xr + l32 + 32);
            v2 = __builtin_nontemporal_load((const vf4*)xr + l32 + 64);
            v3 = __builtin_nontemporal_load((const vf4*)xr + l32 + 96);
        }
        float s = __expf(v0.x) + __expf(v0.y) + __expf(v0.z) + __expf(v0.w)
                + __expf(v1.x) + __expf(v1.y) + __expf(v1.z) + __expf(v1.w)
                + __expf(v2.x) + __expf(v2.y) + __expf(v2.z) + __expf(v2.w)
                + __expf(v3.x) + __expf(v3.y) + __expf(v3.z) + __expf(v3.w);
        #pragma unroll
        for (int d = 1; d < 32; d <<= 1) s += __shfl_xor(s, d);
        float rcp = __builtin_amdgcn_rcpf(s);          // Wb = exp(xb)/s

        float xb = half_get(v0, v1, v2, v3, ib, h);
        int  lbl = __shfl(lbl_l, min(row, 23));
        float xl = half_get(v0, v1, v2, v3, lbl, h);

        size_t cc = cc0 + (size_t)row * (RW + 1);
        if (rv && l32 == 0) D[cc * 2] = __expf(xb) * rcp;
        if (rv && row < nem && l32 == 1)
            D[(cc + 1) * 2 + 1] = __expf(xl + pen) * rcp;
    }
}

// Kernel 2: wavefront DP. One wave per batch. Lane l (0..11) owns the u-strip
// [8l, 8l+7]. Cross-lane shuffle is SOFTWARE-PIPELINED: n7 is computed first
// in each step, its shfl issues immediately, and the result is consumed only
// by the NEXT step's n0 (~8 FMA issues of slack hide the ds_permute latency).
// Stale-by-one-group power-of-2 rescale, bias 2^100 (a7s rescaled too).
__global__ __launch_bounds__(64) void k_alpha(
    const float* __restrict__ D_all,
    const int* __restrict__ f_len, const int* __restrict__ y_len,
    float* __restrict__ out)
{
    const int b = blockIdx.x;
    const int l = threadIdx.x;
    const float* D = D_all + (size_t)b * ROWS * RW * 2;
    const vf4* Dv = (const vf4*)D;                    // 48 vf4 per diag row
    const int lc = (l < 12) ? l : 11;
    const int fcap = f_len[b] - 1;
    const int ycap = y_len[b];
    const int kstar = fcap + ycap;                    // in [135, 350]
    const int gstar = (kstar - 1) >> 3;               // group holding kstar

    float A[8];
    #pragma unroll
    for (int c = 0; c < 8; ++c) A[c] = 0.f;
    if (l == 0) A[0] = 1.f;                           // alpha[0,0] = 1
    float a7s = __shfl_up(A[7], 1);                   // left col 8l-1 value (0)
    int ls_e = 0, E_prev = 0, fls = 0;
    float fin = 0.f;

    vf4 Wa[8][4], Wb[8][4];
    #pragma unroll
    for (int r = 0; r < 8; ++r)
        #pragma unroll
        for (int q = 0; q < 4; ++q)
            Wa[r][q] = Dv[(size_t)r * (RW / 2) + lc * 4 + q];   // rows 0..7

    #define STEP(WROW)                                                    \
    {                                                                     \
        float n7 = fmaf(A[6], (WROW)[3].w, A[7] * (WROW)[3].z);           \
        float n0 = fmaf(a7s,  (WROW)[0].y, A[0] * (WROW)[0].x);           \
        float n1 = fmaf(A[0], (WROW)[0].w, A[1] * (WROW)[0].z);           \
        float n2 = fmaf(A[1], (WROW)[1].y, A[2] * (WROW)[1].x);           \
        float n3 = fmaf(A[2], (WROW)[1].w, A[3] * (WROW)[1].z);           \
        float n4 = fmaf(A[3], (WROW)[2].y, A[4] * (WROW)[2].x);           \
        float n5 = fmaf(A[4], (WROW)[2].w, A[5] * (WROW)[2].z);           \
        float n6 = fmaf(A[5], (WROW)[3].y, A[6] * (WROW)[3].x);           \
        a7s = __shfl_up(n7, 1);                                           \
        A[0]=n0; A[1]=n1; A[2]=n2; A[3]=n3;                               \
        A[4]=n4; A[5]=n5; A[6]=n6; A[7]=n7;                               \
    }

    #define LEAN(CUR, NXT, gg)                                            \
    {                                                                     \
        _Pragma("unroll") for (int r = 0; r < 8; ++r)                     \
            _Pragma("unroll") for (int q = 0; q < 4; ++q)                 \
                NXT[r][q] = Dv[((size_t)((gg)+1)*8 + r)*(RW/2) + lc*4 + q]; \
        _Pragma("unroll") for (int r = 0; r < 8; ++r) STEP(CUR[r]);       \
        int sh = 100 - E_prev;                                            \
        float r1 = exp2i(sh >> 1), r2 = exp2i(sh - (sh >> 1));            \
        _Pragma("unroll") for (int c = 0; c < 8; ++c) A[c] = A[c]*r1*r2;  \
        a7s = a7s * r1 * r2;                                              \
        ls_e += E_prev - 100;                                             \
        float m = fmaxf(fmaxf(fmaxf(A[0],A[1]), fmaxf(A[2],A[3])),        \
                        fmaxf(fmaxf(A[4],A[5]), fmaxf(A[6],A[7])));       \
        m = (l < 12) ? m : 0.f;                                           \
        m = fmaxf(m, __shfl_xor(m, 1));                                   \
        m = fmaxf(m, __shfl_xor(m, 2));                                   \
        m = fmaxf(m, __shfl_xor(m, 4));                                   \
        m = fmaxf(m, __shfl_xor(m, 8));                                   \
        E_prev = (int)((__float_as_uint(m) >> 23) & 0xff) - 127;          \
    }

    #define CAPTURE(CUR, gg)                                              \
    {                                                                     \
        _Pragma("unroll") for (int r = 0; r < 8; ++r) {                   \
            STEP(CUR[r]);                                                 \
            int k = (gg) * 8 + r + 1;                                     \
            if (k == kstar) {                                             \
                int yc = ycap & 7;                                        \
                float f = (yc==0)?A[0]:(yc==1)?A[1]:(yc==2)?A[2]:         \
                          (yc==3)?A[3]:(yc==4)?A[4]:(yc==5)?A[5]:         \
                          (yc==6)?A[6]:A[7];                              \
                fin = (l == (ycap >> 3)) ? f : 0.f;                       \
                fls = ls_e;                                               \
            }                                                             \
        }                                                                 \
    }

    int gg = 0;
    while (true) {
        if (gg == gstar) { CAPTURE(Wa, gg); break; }
        LEAN(Wa, Wb, gg); gg++;
        if (gg == gstar) { CAPTURE(Wb, gg); break; }
        LEAN(Wb, Wa, gg); gg++;
    }
    #undef STEP
    #undef LEAN
    #undef CAPTURE

    float fv = __shfl(fin, ycap >> 3);
    int   fe = __shfl(fls, ycap >> 3);
    if (l == 0) {
        float wbf = D[((size_t)kstar * RW + ycap) * 2];   // e^{blank[fcap,ycap]}
        out[b] = -(__logf(fv) + (float)fe * 0.69314718056f + __logf(wbf));
    }
}

extern "C" void kernel_launch(void* const* d_in, const int* in_sizes, int n_in,
                              void* d_out, int out_size, void* d_ws, size_t ws_size,
                              hipStream_t stream) {
    const float* x      = (const float*)d_in[0];
    const int*   label  = (const int*)d_in[1];
    const int*   f_len  = (const int*)d_in[2];
    const int*   y_len  = (const int*)d_in[3];
    const int*   blankp = (const int*)d_in[4];
    const float* lamp   = (const float*)d_in[5];
    float* out = (float*)d_out;

    float* D = (float*)d_ws;                          // B*ROWS*RW*2 floats

    k_lse<<<2048 + B, 256, 0, stream>>>(x, label, f_len, y_len, blankp, lamp, D);
    k_alpha<<<B, 64, 0, stream>>>(D, f_len, y_len, out);
}

// Round 12
// 72.892 us; speedup vs baseline: 1.0361x; 1.0361x over previous
//
#include <hip/hip_runtime.h>

// RNN-T (transducer) loss, B=8 T=256 U=96 H=512, f32.
// Linear-domain wavefront DP: A[t,u] = A[t-1,u]*Wb[t-1,u] + A[t,u-1]*We[t,u-1]
// Wb=exp(blank_lp), We=exp(emit_lp) precomputed by k_lse into diagonal layout:
// Wb(t,u) -> row t+u, col u, slot0;  We(t,u) -> row t+u, col u+1, slot1.
// Every cell k_alpha reads is zeroed or written each call (no stale/poison).
constexpr int B = 8, T = 256, U = 96, H = 512;
constexpr int RW = 96, ROWS = 368;   // float2 {wb,we} per cell

typedef float vf4 __attribute__((ext_vector_type(4)));

__device__ __forceinline__ float exp2i(int e) {      // e in [-126,127]
    return __uint_as_float((unsigned)(127 + e) << 23);
}

// x + dpp_shifted(x): rocPRIM-style wave64 reduce building block.
#define DPPADD(x, ctrl)                                                     \
    ((x) + __int_as_float(__builtin_amdgcn_update_dpp(                      \
               0, __float_as_int(x), (ctrl), 0xf, 0xf, true)))

// Kernel 1: blocks <2048: one wave per 24-row chunk, one 512-elem row per
// iteration (8 floats/lane), 1-row lookahead prefetch, DPP-tree reduce
// (no LDS/ds_permute on the critical path). Blocks >=2048: zero unowned
// cells (triangles, tail rows, col-0 We slots).
__global__ __launch_bounds__(256) void k_lse(
    const float* __restrict__ x, const int* __restrict__ label,
    const int* __restrict__ f_len, const int* __restrict__ y_len,
    const int* __restrict__ blank_p, const float* __restrict__ lam_p,
    float* __restrict__ D)
{
    const int tid = threadIdx.x;
    if (blockIdx.x >= 2048) {            // zero-fill unowned cells, batch bb
        int bb = blockIdx.x - 2048;
        float2* D2 = (float2*)D + (size_t)bb * ROWS * RW;
        float2 z = {0.f, 0.f};
        for (int k = 0; k < 95; ++k)                 // cells (k,c), c>k
            if (tid < 95 - k) D2[k * RW + k + 1 + tid] = z;
        for (int k = 256; k < 351; ++k)              // cells (k,c), c<k-255
            if (tid < k - 255) D2[k * RW + tid] = z;
        for (int idx = tid; idx < 17 * RW; idx += 256)  // tail rows 351..367
            D2[351 * RW + idx] = z;
        if (tid < 256)                               // col-0 We(t,-1) slots
            ((float*)&D2[tid * RW])[1] = 0.f;
        return;
    }

    const int lane = tid & 63;
    const int chunk = (blockIdx.x << 2) | (tid >> 6);   // 0..8191
    const int b  = chunk & 7;                 // b fastest: balanced dead work
    const int t  = (chunk >> 3) & 255;
    const int u0 = (chunk >> 11) * 24;

    const int fb = f_len[b], yb = y_len[b];
    const bool live = (t < fb) && (u0 <= yb);
    const int nbl = live ? min(24, yb + 1 - u0) : 0;   // rows with Wb write
    const int nem = live ? min(24, yb - u0)     : 0;   // rows with We write

    size_t cc0 = ((size_t)b * ROWS + (t + u0)) * RW + u0;
    if (lane < 24) {                       // zero owned-but-unwritten slots
        size_t cz = cc0 + (size_t)lane * (RW + 1);
        if (lane >= nbl) D[cz * 2] = 0.f;
        if (lane >= nem) D[(cz + 1) * 2 + 1] = 0.f;
    }
    if (!live) return;

    const int ib   = blank_p[0];
    const float lam = lam_p[0];
    const float pen = lam * ((fb - 1.0f) * 0.5f) - lam * (float)t;

    int lbl_l = 0;                                     // labels u0..u0+23
    if (lane < 24 && (u0 + lane) < U - 1)
        lbl_l = label[b * (U - 1) + u0 + lane];

    const float* xrow = x + ((size_t)(b * T + t) * U + u0) * H;

    vf4 c0 = __builtin_nontemporal_load((const vf4*)xrow + lane);
    vf4 c1 = __builtin_nontemporal_load((const vf4*)xrow + lane + 64);

    for (int i = 0; i < nbl; ++i) {
        vf4 n0, n1;
        if (i + 1 < nbl) {                 // prefetch next row
            const float* xn = xrow + (size_t)(i + 1) * H;
            n0 = __builtin_nontemporal_load((const vf4*)xn + lane);
            n1 = __builtin_nontemporal_load((const vf4*)xn + lane + 64);
        }
        float s = __expf(c0.x) + __expf(c0.y) + __expf(c0.z) + __expf(c0.w)
                + __expf(c1.x) + __expf(c1.y) + __expf(c1.z) + __expf(c1.w);
        s = DPPADD(s, 0x111);              // row_shr:1
        s = DPPADD(s, 0x112);              // row_shr:2
        s = DPPADD(s, 0x114);              // row_shr:4
        s = DPPADD(s, 0x118);              // row_shr:8
        s = DPPADD(s, 0x142);              // row_bcast:15
        s = DPPADD(s, 0x143);              // row_bcast:31 -> lane 63 = total
        float sum = __int_as_float(
            __builtin_amdgcn_readlane(__float_as_int(s), 63));
        float rcp = __builtin_amdgcn_rcpf(sum);        // W = exp(x)/sum

        // extract x[ib] via per-lane select + readlane (no ds_bpermute)
        vf4 vb = (ib < 256) ? c0 : c1;
        float cb = (ib & 2) ? ((ib & 1) ? vb.w : vb.z)
                            : ((ib & 1) ? vb.y : vb.x);
        float xb = __int_as_float(__builtin_amdgcn_readlane(
            __float_as_int(cb), (ib >> 2) & 63));

        int lbl = __builtin_amdgcn_readlane(lbl_l, i < 24 ? i : 23);
        vf4 vl = (lbl < 256) ? c0 : c1;
        float cl = (lbl & 2) ? ((lbl & 1) ? vl.w : vl.z)
                             : ((lbl & 1) ? vl.y : vl.x);
        float xl = __int_as_float(__builtin_amdgcn_readlane(
            __float_as_int(cl), (lbl >> 2) & 63));

        size_t cc = cc0 + (size_t)i * (RW + 1);
        if (lane == 0) D[cc * 2] = __expf(xb) * rcp;            // Wb(t,u)
        if (lane == 1 && i < nem)
            D[(cc + 1) * 2 + 1] = __expf(xl + pen) * rcp;       // We(t,u)
        c0 = n0; c1 = n1;
    }
}

// Kernel 2: wavefront DP (R9-proven form). One wave per batch. Lane l
// (0..11) owns u-strip [8l, 8l+7]; per step 1 shfl_up + 8 FMA-pairs.
// Stale-by-one-group power-of-2 rescale, bias 2^100.
__global__ __launch_bounds__(64) void k_alpha(
    const float* __restrict__ D_all,
    const int* __restrict__ f_len, const int* __restrict__ y_len,
    float* __restrict__ out)
{
    const int b = blockIdx.x;
    const int l = threadIdx.x;
    const float* D = D_all + (size_t)b * ROWS * RW * 2;
    const vf4* Dv = (const vf4*)D;                    // 48 vf4 per diag row
    const int lc = (l < 12) ? l : 11;
    const int fcap = f_len[b] - 1;
    const int ycap = y_len[b];
    const int kstar = fcap + ycap;                    // in [135, 350]
    const int gstar = (kstar - 1) >> 3;               // group holding kstar

    float A[8];
    #pragma unroll
    for (int c = 0; c < 8; ++c) A[c] = 0.f;
    if (l == 0) A[0] = 1.f;                           // alpha[0,0] = 1
    int ls_e = 0, E_prev = 0, fls = 0;
    float fin = 0.f;

    vf4 Wa[8][4], Wb[8][4];
    #pragma unroll
    for (int r = 0; r < 8; ++r)
        #pragma unroll
        for (int q = 0; q < 4; ++q)
            Wa[r][q] = Dv[(size_t)r * (RW / 2) + lc * 4 + q];   // rows 0..7

    #define STEP(WROW)                                                    \
    {                                                                     \
        float a7s = __shfl_up(A[7], 1);                                   \
        float n0 = fmaf(a7s,  (WROW)[0].y, A[0] * (WROW)[0].x);           \
        float n1 = fmaf(A[0], (WROW)[0].w, A[1] * (WROW)[0].z);           \
        float n2 = fmaf(A[1], (WROW)[1].y, A[2] * (WROW)[1].x);           \
        float n3 = fmaf(A[2], (WROW)[1].w, A[3] * (WROW)[1].z);           \
        float n4 = fmaf(A[3], (WROW)[2].y, A[4] * (WROW)[2].x);           \
        float n5 = fmaf(A[4], (WROW)[2].w, A[5] * (WROW)[2].z);           \
        float n6 = fmaf(A[5], (WROW)[3].y, A[6] * (WROW)[3].x);           \
        float n7 = fmaf(A[6], (WROW)[3].w, A[7] * (WROW)[3].z);           \
        A[0]=n0; A[1]=n1; A[2]=n2; A[3]=n3;                               \
        A[4]=n4; A[5]=n5; A[6]=n6; A[7]=n7;                               \
    }

    #define LEAN(CUR, NXT, gg)                                            \
    {                                                                     \
        _Pragma("unroll") for (int r = 0; r < 8; ++r)                     \
            _Pragma("unroll") for (int q = 0; q < 4; ++q)                 \
                NXT[r][q] = Dv[((size_t)((gg)+1)*8 + r)*(RW/2) + lc*4 + q]; \
        _Pragma("unroll") for (int r = 0; r < 8; ++r) STEP(CUR[r]);       \
        int sh = 100 - E_prev;                                            \
        float r1 = exp2i(sh >> 1), r2 = exp2i(sh - (sh >> 1));            \
        _Pragma("unroll") for (int c = 0; c < 8; ++c) A[c] = A[c]*r1*r2;  \
        ls_e += E_prev - 100;                                             \
        float m = fmaxf(fmaxf(fmaxf(A[0],A[1]), fmaxf(A[2],A[3])),        \
                        fmaxf(fmaxf(A[4],A[5]), fmaxf(A[6],A[7])));       \
        m = (l < 12) ? m : 0.f;                                           \
        m = fmaxf(m, __shfl_xor(m, 1));                                   \
        m = fmaxf(m, __shfl_xor(m, 2));                                   \
        m = fmaxf(m, __shfl_xor(m, 4));                                   \
        m = fmaxf(m, __shfl_xor(m, 8));                                   \
        E_prev = (int)((__float_as_uint(m) >> 23) & 0xff) - 127;          \
    }

    #define CAPTURE(CUR, gg)                                              \
    {                                                                     \
        _Pragma("unroll") for (int r = 0; r < 8; ++r) {                   \
            STEP(CUR[r]);                                                 \
            int k = (gg) * 8 + r + 1;                                     \
            if (k == kstar) {                                             \
                int yc = ycap & 7;                                        \
                float f = (yc==0)?A[0]:(yc==1)?A[1]:(yc==2)?A[2]:         \
                          (yc==3)?A[3]:(yc==4)?A[4]:(yc==5)?A[5]:         \
                          (yc==6)?A[6]:A[7];                              \
                fin = (l == (ycap >> 3)) ? f : 0.f;                       \
                fls = ls_e;                                               \
            }                                                             \
        }                                                                 \
    }

    int gg = 0;
    while (true) {
        if (gg == gstar) { CAPTURE(Wa, gg); break; }
        LEAN(Wa, Wb, gg); gg++;
        if (gg == gstar) { CAPTURE(Wb, gg); break; }
        LEAN(Wb, Wa, gg); gg++;
    }
    #undef STEP
    #undef LEAN
    #undef CAPTURE

    float fv = __shfl(fin, ycap >> 3);
    int   fe = __shfl(fls, ycap >> 3);
    if (l == 0) {
        float wbf = D[((size_t)kstar * RW + ycap) * 2];   // e^{blank[fcap,ycap]}
        out[b] = -(__logf(fv) + (float)fe * 0.69314718056f + __logf(wbf));
    }
}

extern "C" void kernel_launch(void* const* d_in, const int* in_sizes, int n_in,
                              void* d_out, int out_size, void* d_ws, size_t ws_size,
                              hipStream_t stream) {
    const float* x      = (const float*)d_in[0];
    const int*   label  = (const int*)d_in[1];
    const int*   f_len  = (const int*)d_in[2];
    const int*   y_len  = (const int*)d_in[3];
    const int*   blankp = (const int*)d_in[4];
    const float* lamp   = (const float*)d_in[5];
    float* out = (float*)d_out;

    float* D = (float*)d_ws;                          // B*ROWS*RW*2 floats

    k_lse<<<2048 + B, 256, 0, stream>>>(x, label, f_len, y_len, blankp, lamp, D);
    k_alpha<<<B, 64, 0, stream>>>(D, f_len, y_len, out);
}

// Round 13
// 68.148 us; speedup vs baseline: 1.1083x; 1.0696x over previous
//
#include <hip/hip_runtime.h>

// RNN-T (transducer) loss, B=8 T=256 U=96 H=512, f32.
// Linear-domain wavefront DP: A[t,u] = A[t-1,u]*Wb[t-1,u] + A[t,u-1]*We[t,u-1]
// Wb=exp(blank_lp), We=exp(emit_lp) precomputed by k_lse into diagonal layout:
// Wb(t,u) -> row t+u, col u, slot0;  We(t,u) -> row t+u, col u+1, slot1.
// Every cell k_alpha reads is zeroed or written each call (no stale/poison).
constexpr int B = 8, T = 256, U = 96, H = 512;
constexpr int RW = 96, ROWS = 368;   // float2 {wb,we} per cell
constexpr int CH = 12;               // rows per k_lse chunk (straggler bound)

typedef float vf4 __attribute__((ext_vector_type(4)));

__device__ __forceinline__ float exp2i(int e) {      // e in [-126,127]
    return __uint_as_float((unsigned)(127 + e) << 23);
}

// Fetch row element i (uniform per half) from a 32-lane half's registers.
__device__ __forceinline__ float half_get(vf4 a, vf4 b, vf4 c, vf4 d,
                                          int i, int h) {
    vf4 p = (i & 128) ? ((i & 256) ? d : b) : ((i & 256) ? c : a);
    int m = i & 3;
    float e = (m == 0) ? p.x : (m == 1) ? p.y : (m == 2) ? p.z : p.w;
    return __shfl(e, (h << 5) | ((i >> 2) & 31));
}

// Kernel 1: blocks <4096: one wave per 12-row chunk, 2 rows at a time via
// 32-lane halves (5-level reduce). Blocks >=4096: zero unowned cells
// (triangles, tail rows, col-0 We slots). __launch_bounds__(256,8) pins
// VGPR<=64 so all 4 waves/block x 8 blocks/CU are resident (32 waves/CU).
__global__ __launch_bounds__(256, 8) void k_lse(
    const float* __restrict__ x, const int* __restrict__ label,
    const int* __restrict__ f_len, const int* __restrict__ y_len,
    const int* __restrict__ blank_p, const float* __restrict__ lam_p,
    float* __restrict__ D)
{
    const int tid = threadIdx.x;
    if (blockIdx.x >= 4096) {            // zero-fill unowned cells, batch bb
        int bb = blockIdx.x - 4096;
        float2* D2 = (float2*)D + (size_t)bb * ROWS * RW;
        float2 z = {0.f, 0.f};
        for (int k = 0; k < 95; ++k)                 // cells (k,c), c>k
            if (tid < 95 - k) D2[k * RW + k + 1 + tid] = z;
        for (int k = 256; k < 351; ++k)              // cells (k,c), c<k-255
            if (tid < k - 255) D2[k * RW + tid] = z;
        for (int idx = tid; idx < 17 * RW; idx += 256)  // tail rows 351..367
            D2[351 * RW + idx] = z;
        if (tid < 256)                               // col-0 We(t,-1) slots
            ((float*)&D2[tid * RW])[1] = 0.f;
        return;
    }

    const int lane = tid & 63;
    const int l32  = lane & 31;
    const int h    = lane >> 5;
    const int chunk = (blockIdx.x << 2) | (tid >> 6);   // 0..16383
    const int b  = chunk & 7;                 // b fastest: balanced dead work
    const int t  = (chunk >> 3) & 255;
    const int u0 = (chunk >> 11) * CH;        // 0,12,...,84

    const int fb = f_len[b], yb = y_len[b];
    const bool live = (t < fb) && (u0 <= yb);
    const int nbl = live ? min(CH, yb + 1 - u0) : 0;   // rows with Wb write
    const int nem = live ? min(CH, yb - u0)     : 0;   // rows with We write

    size_t cc0 = ((size_t)b * ROWS + (t + u0)) * RW + u0;
    if (lane < CH) {                       // zero owned-but-unwritten slots
        size_t cz = cc0 + (size_t)lane * (RW + 1);
        if (lane >= nbl) D[cz * 2] = 0.f;
        if (lane >= nem) D[(cz + 1) * 2 + 1] = 0.f;
    }
    if (!live) return;

    const int ib   = blank_p[0];
    const float lam = lam_p[0];
    const float pen = lam * ((fb - 1.0f) * 0.5f) - lam * (float)t;

    int lbl_l = 0;                                     // labels u0..u0+11
    if (lane < CH && (u0 + lane) < U - 1)
        lbl_l = label[b * (U - 1) + u0 + lane];

    const float* xrow = x + ((size_t)(b * T + t) * U + u0) * H;

    for (int i = 0; i < nbl; i += 2) {
        int row = i + h;                   // half h handles row i+h
        bool rv = row < nbl;
        const float* xr = xrow + (size_t)row * H;
        vf4 v0 = {0,0,0,0}, v1 = v0, v2 = v0, v3 = v0;
        if (rv) {
            v0 = __builtin_nontemporal_load((const vf4*)xr + l32);
            v1 = __builtin_nontemporal_load((const vf4*)xr + l32 + 32);
            v2 = __builtin_nontemporal_load((const vf4*)xr + l32 + 64);
            v3 = __builtin_nontemporal_load((const vf4*)xr + l32 + 96);
        }
        float s = __expf(v0.x) + __expf(v0.y) + __expf(v0.z) + __expf(v0.w)
                + __expf(v1.x) + __expf(v1.y) + __expf(v1.z) + __expf(v1.w)
                + __expf(v2.x) + __expf(v2.y) + __expf(v2.z) + __expf(v2.w)
                + __expf(v3.x) + __expf(v3.y) + __expf(v3.z) + __expf(v3.w);
        #pragma unroll
        for (int d = 1; d < 32; d <<= 1) s += __shfl_xor(s, d);
        float rcp = __builtin_amdgcn_rcpf(s);          // W = exp(x)/s

        float xb = half_get(v0, v1, v2, v3, ib, h);
        int  lbl = __shfl(lbl_l, min(row, CH - 1));
        float xl = half_get(v0, v1, v2, v3, lbl, h);

        size_t cc = cc0 + (size_t)row * (RW + 1);
        if (rv && l32 == 0) D[cc * 2] = __expf(xb) * rcp;
        if (rv && row < nem && l32 == 1)
            D[(cc + 1) * 2 + 1] = __expf(xl + pen) * rcp;
    }
}

// Kernel 2: wavefront DP. One wave per batch. Lane l (0..11) owns the u-strip
// [8l, 8l+7]. Cross-lane shuffle is software-pipelined: n7 computed first,
// its shfl issues immediately, consumed by the NEXT step's n0.
// Stale-by-one-group power-of-2 rescale, bias 2^100 (a7s rescaled too).
__global__ __launch_bounds__(64) void k_alpha(
    const float* __restrict__ D_all,
    const int* __restrict__ f_len, const int* __restrict__ y_len,
    float* __restrict__ out)
{
    const int b = blockIdx.x;
    const int l = threadIdx.x;
    const float* D = D_all + (size_t)b * ROWS * RW * 2;
    const vf4* Dv = (const vf4*)D;                    // 48 vf4 per diag row
    const int lc = (l < 12) ? l : 11;
    const int fcap = f_len[b] - 1;
    const int ycap = y_len[b];
    const int kstar = fcap + ycap;                    // in [135, 350]
    const int gstar = (kstar - 1) >> 3;               // group holding kstar

    float A[8];
    #pragma unroll
    for (int c = 0; c < 8; ++c) A[c] = 0.f;
    if (l == 0) A[0] = 1.f;                           // alpha[0,0] = 1
    float a7s = __shfl_up(A[7], 1);                   // left col 8l-1 value (0)
    int ls_e = 0, E_prev = 0, fls = 0;
    float fin = 0.f;

    vf4 Wa[8][4], Wb[8][4];
    #pragma unroll
    for (int r = 0; r < 8; ++r)
        #pragma unroll
        for (int q = 0; q < 4; ++q)
            Wa[r][q] = Dv[(size_t)r * (RW / 2) + lc * 4 + q];   // rows 0..7

    #define STEP(WROW)                                                    \
    {                                                                     \
        float n7 = fmaf(A[6], (WROW)[3].w, A[7] * (WROW)[3].z);           \
        float n0 = fmaf(a7s,  (WROW)[0].y, A[0] * (WROW)[0].x);           \
        float n1 = fmaf(A[0], (WROW)[0].w, A[1] * (WROW)[0].z);           \
        float n2 = fmaf(A[1], (WROW)[1].y, A[2] * (WROW)[1].x);           \
        float n3 = fmaf(A[2], (WROW)[1].w, A[3] * (WROW)[1].z);           \
        float n4 = fmaf(A[3], (WROW)[2].y, A[4] * (WROW)[2].x);           \
        float n5 = fmaf(A[4], (WROW)[2].w, A[5] * (WROW)[2].z);           \
        float n6 = fmaf(A[5], (WROW)[3].y, A[6] * (WROW)[3].x);           \
        a7s = __shfl_up(n7, 1);                                           \
        A[0]=n0; A[1]=n1; A[2]=n2; A[3]=n3;                               \
        A[4]=n4; A[5]=n5; A[6]=n6; A[7]=n7;                               \
    }

    #define LEAN(CUR, NXT, gg)                                            \
    {                                                                     \
        _Pragma("unroll") for (int r = 0; r < 8; ++r)                     \
            _Pragma("unroll") for (int q = 0; q < 4; ++q)                 \
                NXT[r][q] = Dv[((size_t)((gg)+1)*8 + r)*(RW/2) + lc*4 + q]; \
        _Pragma("unroll") for (int r = 0; r < 8; ++r) STEP(CUR[r]);       \
        int sh = 100 - E_prev;                                            \
        float r1 = exp2i(sh >> 1), r2 = exp2i(sh - (sh >> 1));            \
        _Pragma("unroll") for (int c = 0; c < 8; ++c) A[c] = A[c]*r1*r2;  \
        a7s = a7s * r1 * r2;                                              \
        ls_e += E_prev - 100;                                             \
        float m = fmaxf(fmaxf(fmaxf(A[0],A[1]), fmaxf(A[2],A[3])),        \
                        fmaxf(fmaxf(A[4],A[5]), fmaxf(A[6],A[7])));       \
        m = (l < 12) ? m : 0.f;                                           \
        m = fmaxf(m, __shfl_xor(m, 1));                                   \
        m = fmaxf(m, __shfl_xor(m, 2));                                   \
        m = fmaxf(m, __shfl_xor(m, 4));                                   \
        m = fmaxf(m, __shfl_xor(m, 8));                                   \
        E_prev = (int)((__float_as_uint(m) >> 23) & 0xff) - 127;          \
    }

    #define CAPTURE(CUR, gg)                                              \
    {                                                                     \
        _Pragma("unroll") for (int r = 0; r < 8; ++r) {                   \
            STEP(CUR[r]);                                                 \
            int k = (gg) * 8 + r + 1;                                     \
            if (k == kstar) {                                             \
                int yc = ycap & 7;                                        \
                float f = (yc==0)?A[0]:(yc==1)?A[1]:(yc==2)?A[2]:         \
                          (yc==3)?A[3]:(yc==4)?A[4]:(yc==5)?A[5]:         \
                          (yc==6)?A[6]:A[7];                              \
                fin = (l == (ycap >> 3)) ? f : 0.f;                       \
                fls = ls_e;                                               \
            }                                                             \
        }                                                                 \
    }

    int gg = 0;
    while (true) {
        if (gg == gstar) { CAPTURE(Wa, gg); break; }
        LEAN(Wa, Wb, gg); gg++;
        if (gg == gstar) { CAPTURE(Wb, gg); break; }
        LEAN(Wb, Wa, gg); gg++;
    }
    #undef STEP
    #undef LEAN
    #undef CAPTURE

    float fv = __shfl(fin, ycap >> 3);
    int   fe = __shfl(fls, ycap >> 3);
    if (l == 0) {
        float wbf = D[((size_t)kstar * RW + ycap) * 2];   // e^{blank[fcap,ycap]}
        out[b] = -(__logf(fv) + (float)fe * 0.69314718056f + __logf(wbf));
    }
}

extern "C" void kernel_launch(void* const* d_in, const int* in_sizes, int n_in,
                              void* d_out, int out_size, void* d_ws, size_t ws_size,
                              hipStream_t stream) {
    const float* x      = (const float*)d_in[0];
    const int*   label  = (const int*)d_in[1];
    const int*   f_len  = (const int*)d_in[2];
    const int*   y_len  = (const int*)d_in[3];
    const int*   blankp = (const int*)d_in[4];
    const float* lamp   = (const float*)d_in[5];
    float* out = (float*)d_out;

    float* D = (float*)d_ws;                          // B*ROWS*RW*2 floats

    k_lse<<<4096 + B, 256, 0, stream>>>(x, label, f_len, y_len, blankp, lamp, D);
    k_alpha<<<B, 64, 0, stream>>>(D, f_len, y_len, out);
}